// Round 5
// baseline (262.663 us; speedup 1.0000x reference)
//
#include <hip/hip_runtime.h>

#define BATCH 2048
#define VOCAB 256
#define KDIM 16384
#define BM 64
#define BK 64
#define S_SPLIT 32
#define KCHUNK (KDIM / S_SPLIT)  // 512
#define NT (KCHUNK / BK)         // 8 K-steps per block
#define LN10 2.302585092994046f

typedef __attribute__((ext_vector_type(8))) short short8;
typedef __attribute__((ext_vector_type(4))) float f32x4;

#define FENCE asm volatile("" ::: "memory")

__device__ __forceinline__ unsigned short f2bf_rne(float f) {
  unsigned int u = __float_as_uint(f);
  u += 0x7fffu + ((u >> 16) & 1u);
  return (unsigned short)(u >> 16);
}
// binary values are exactly 0.0f/1.0f -> truncation is exact
__device__ __forceinline__ unsigned int pack2(float lo, float hi) {
  return (__float_as_uint(lo) >> 16) | (__float_as_uint(hi) & 0xffff0000u);
}

__device__ __forceinline__ void async16(void* lds, const void* g) {
  __builtin_amdgcn_global_load_lds(
      (const __attribute__((address_space(1))) unsigned int*)g,
      (__attribute__((address_space(3))) unsigned int*)lds, 16, 0, 0);
}

// ---------------- log_w precompute: logw = bf16(log(10*sigmoid(raw))) -------
__global__ __launch_bounds__(256) void k_logw(const float* __restrict__ raw,
                                              unsigned short* __restrict__ logw) {
  int i = blockIdx.x * 256 + threadIdx.x; // float4 index, exact grid
  float4 x = ((const float4*)raw)[i];
  ushort4 r;
  r.x = f2bf_rne(LN10 - log1pf(expf(-x.x)));
  r.y = f2bf_rne(LN10 - log1pf(expf(-x.y)));
  r.z = f2bf_rne(LN10 - log1pf(expf(-x.z)));
  r.w = f2bf_rne(LN10 - log1pf(expf(-x.w)));
  ((ushort4*)logw)[i] = r;
}

// ---------------- main K-split MFMA GEMM (m97-shaped) -----------------------
// grid (32 splits, 32 m-blocks) = 1024 blocks; 256 thr (4 waves); LDS 40 KB
// single-buffered -> 3+ resident blocks/CU (cross-block overlap hides drain).
// Wave = 64x64 quadrant (4x4 16x16x32 frags). A reg-staged fp32->bf16; B via
// global_load_lds (linear dest, pre-swizzled source). 8-slot XOR swizzle on
// 128-B LDS rows: phys_slot = slot ^ (row&7)  (slot = 16 B).
// PART=1: unique-writer partials; PART=0: atomicAdd fallback.
template <int PART>
__global__ __launch_bounds__(256, 3) void k_gemm(
    const float* __restrict__ binary, const unsigned short* __restrict__ logw,
    float* __restrict__ outp, float* __restrict__ nactp) {
  __shared__ char smem[40960];
  char* const Asm = smem;          // [64][128 B]
  char* const Bsm = smem + 8192;   // [256][128 B]

  const int tid = threadIdx.x;
  const int wv = tid >> 6;
  const int lane = tid & 63;
  const int l15 = lane & 15;
  const int lhi = lane >> 4;
  const int sx = blockIdx.x;  // k-split
  const int my = blockIdx.y;  // m-block
  const int m0 = my * BM;
  const int k0 = sx * KCHUNK;

  // A: thread -> row ar (4 thr/row), 16 floats at col ac*16
  const int ar = tid >> 2, ac = tid & 3;
  const float* asrc = binary + (size_t)(m0 + ar) * KDIM + k0 + ac * 16;
  const int ar7 = ar & 7;
  const int aw0 = ar * 128 + ((((ac * 2) ^ ar7) << 4));
  const int aw1 = ar * 128 + ((((ac * 2 + 1) ^ ar7) << 4));

  // B glds: instr i covers rows wv*64+i*8+(lane>>3); src slot pre-swizzled
  const unsigned short* bsrc =
      logw + (size_t)(wv * 64 + (lane >> 3)) * KDIM + k0 +
      (((lane & 7) ^ (lane >> 3)) << 3);

  // LDS read: koff = (ks*64 + lhi*16) ^ ((l15&7)<<4)
  const int rsw = (l15 & 7) << 4;

  f32x4 acc[4][4];
#pragma unroll
  for (int m = 0; m < 4; ++m)
#pragma unroll
    for (int n = 0; n < 4; ++n) acc[m][n] = f32x4{0.f, 0.f, 0.f, 0.f};
  float asum = 0.f;
  float4 Ra[4], Rb[4];

  auto ALOAD = [&](int t, float4* R) {
    const float4* p = (const float4*)(asrc + t * BK);
    R[0] = p[0]; R[1] = p[1]; R[2] = p[2]; R[3] = p[3];
  };
  auto BSTAGE = [&](int t) {
#pragma unroll
    for (int i = 0; i < 8; ++i)
      async16(Bsm + (wv * 64 + i * 8) * 128, bsrc + (size_t)i * 8 * KDIM + t * BK);
  };
  auto AWRITE = [&](const float4* R) {
#pragma unroll
    for (int j = 0; j < 4; ++j)
      asum += R[j].x + R[j].y + R[j].z + R[j].w;
    uint4 u0, u1;
    u0.x = pack2(R[0].x, R[0].y); u0.y = pack2(R[0].z, R[0].w);
    u0.z = pack2(R[1].x, R[1].y); u0.w = pack2(R[1].z, R[1].w);
    u1.x = pack2(R[2].x, R[2].y); u1.y = pack2(R[2].z, R[2].w);
    u1.z = pack2(R[3].x, R[3].y); u1.w = pack2(R[3].z, R[3].w);
    *(uint4*)(Asm + aw0) = u0;
    *(uint4*)(Asm + aw1) = u1;
  };
  auto COMPUTE = [&]() {
#pragma unroll
    for (int ks = 0; ks < 2; ++ks) {
      const int koff = ((ks * 64) | (lhi * 16)) ^ rsw;
      short8 af[4], bf[4];
#pragma unroll
      for (int m = 0; m < 4; ++m)
        af[m] = *(const short8*)(Asm + (m * 16 + l15) * 128 + koff);
#pragma unroll
      for (int n = 0; n < 4; ++n)
        bf[n] = *(const short8*)(Bsm + (wv * 64 + n * 16 + l15) * 128 + koff);
      // swapped operands: D row = vocab-local, D col = batch-local (l15)
#pragma unroll
      for (int m = 0; m < 4; ++m)
#pragma unroll
        for (int n = 0; n < 4; ++n)
          acc[m][n] = __builtin_amdgcn_mfma_f32_16x16x32_bf16(bf[n], af[m],
                                                              acc[m][n], 0, 0, 0);
    }
  };

#define VMW4 asm volatile("s_waitcnt vmcnt(4) lgkmcnt(0)" ::: "memory")
#define BAR __builtin_amdgcn_s_barrier()

  ALOAD(0, Ra);
#pragma unroll 1
  for (int t = 0; t < NT; t += 2) {
    // even: stage tile t, prefetch A(t+1); compute tile t
    BSTAGE(t);
    AWRITE(Ra);               // compiler waits Ra's 4 loads (vmcnt(8))
    ALOAD(t + 1, Rb);         // stays in flight across compute
    VMW4; BAR; FENCE;
    COMPUTE();
    FENCE; BAR; FENCE;
    // odd: stage tile t+1, prefetch A(t+2, clamped); compute tile t+1
    BSTAGE(t + 1);
    AWRITE(Rb);
    ALOAD(t + 2 < NT ? t + 2 : NT - 1, Ra); // clamp keeps vm-counts uniform
    VMW4; BAR; FENCE;
    COMPUTE();
    FENCE; BAR; FENCE;
  }

  // n_active: threads 4r..4r+3 hold row r's partial sums
  float s = asum;
  s += __shfl_xor(s, 1, 64);
  s += __shfl_xor(s, 2, 64);

  if (PART) {
    if (ac == 0) nactp[sx * BATCH + m0 + ar] = s;
    // D layout (swapped): vocab = wv*64 + n*16 + lhi*4 + i, batch = m*16 + l15
#pragma unroll
    for (int m = 0; m < 4; ++m) {
      float* dst = outp + ((size_t)sx * BATCH + m0 + m * 16 + l15) * VOCAB +
                   wv * 64 + lhi * 4;
#pragma unroll
      for (int n = 0; n < 4; ++n)
        *(float4*)(dst + n * 16) =
            (float4){acc[m][n][0], acc[m][n][1], acc[m][n][2], acc[m][n][3]};
    }
  } else {
    if (ac == 0) atomicAdd(&nactp[m0 + ar], s);
#pragma unroll
    for (int m = 0; m < 4; ++m)
#pragma unroll
      for (int n = 0; n < 4; ++n)
#pragma unroll
        for (int i = 0; i < 4; ++i)
          atomicAdd(&outp[(size_t)(m0 + m * 16 + l15) * VOCAB + wv * 64 +
                          n * 16 + lhi * 4 + i],
                    acc[m][n][i]);
  }
}

// ---------------- reduce (partial path): sum splits, divide, exp ------------
__global__ __launch_bounds__(256) void k_reduce(const float* __restrict__ part,
                                                const float* __restrict__ nactp,
                                                float* __restrict__ out) {
  int b = blockIdx.x;
  int v = threadIdx.x;
  float sum = 0.f, n = 0.f;
#pragma unroll
  for (int i = 0; i < S_SPLIT; ++i) {
    sum += part[((size_t)i * BATCH + b) * VOCAB + v];
    n += nactp[i * BATCH + b];
  }
  out[(size_t)b * VOCAB + v] = expf(sum / fmaxf(n, 1.f));
}

// ---------------- epilogue (atomic fallback path) ---------------------------
__global__ __launch_bounds__(256) void k_out(float* __restrict__ io,
                                             const float* __restrict__ nact) {
  int b = blockIdx.x;
  int v = threadIdx.x;
  float n = fmaxf(nact[b], 1.0f);
  size_t idx = (size_t)b * VOCAB + v;
  io[idx] = expf(io[idx] / n);
}

extern "C" void kernel_launch(void* const* d_in, const int* in_sizes, int n_in,
                              void* d_out, int out_size, void* d_ws, size_t ws_size,
                              hipStream_t stream) {
  const float* binary = (const float*)d_in[0];
  const float* raw = (const float*)d_in[1];
  float* out = (float*)d_out;
  char* ws = (char*)d_ws;

  const size_t LOGW_B = (size_t)VOCAB * KDIM * 2;            // 8 MB
  const size_t NACT_B = (size_t)S_SPLIT * BATCH * 4;         // 256 KB
  const size_t PART_B = (size_t)S_SPLIT * BATCH * VOCAB * 4; // 64 MB
  unsigned short* logw = (unsigned short*)ws;
  float* nactp = (float*)(ws + LOGW_B);
  float* part = (float*)(ws + LOGW_B + NACT_B);

  k_logw<<<(VOCAB * KDIM / 4) / 256, 256, 0, stream>>>(raw, logw);

  dim3 g(S_SPLIT, BATCH / BM);
  if (ws_size >= LOGW_B + NACT_B + PART_B) {
    k_gemm<1><<<g, 256, 0, stream>>>(binary, logw, part, nactp);
    k_reduce<<<BATCH, VOCAB, 0, stream>>>(part, nactp, out);
  } else {
    hipMemsetAsync(out, 0, (size_t)BATCH * VOCAB * sizeof(float), stream);
    hipMemsetAsync(nactp, 0, BATCH * sizeof(float), stream);
    k_gemm<0><<<g, 256, 0, stream>>>(binary, logw, out, nactp);
    k_out<<<BATCH, VOCAB, 0, stream>>>(out, nactp);
  }
}

// Round 6
// 243.536 us; speedup vs baseline: 1.0785x; 1.0785x over previous
//
#include <hip/hip_runtime.h>

#define BATCH 2048
#define VOCAB 256
#define KDIM 16384
#define WPR (KDIM / 32)          // 512 bit-words per row
#define BM 64
#define BK 64
#define S_SPLIT 16
#define KCHUNK (KDIM / S_SPLIT)  // 1024
#define NT (KCHUNK / BK)         // 16 K-tiles per block
#define CW (KCHUNK / 32)         // 32 words per row per chunk
#define LN10 2.302585092994046f

typedef __attribute__((ext_vector_type(8))) short short8;
typedef __attribute__((ext_vector_type(4))) float f32x4;

#define FENCE asm volatile("" ::: "memory")
#define BAR __builtin_amdgcn_s_barrier()
#define VMW8 asm volatile("s_waitcnt vmcnt(8)" ::: "memory")
#define VMW0 asm volatile("s_waitcnt vmcnt(0)" ::: "memory")

__device__ __forceinline__ unsigned short f2bf_rne(float f) {
  unsigned int u = __float_as_uint(f);
  u += 0x7fffu + ((u >> 16) & 1u);
  return (unsigned short)(u >> 16);
}

__device__ __forceinline__ void async16(void* lds, const void* g) {
  __builtin_amdgcn_global_load_lds(
      (const __attribute__((address_space(1))) unsigned int*)g,
      (__attribute__((address_space(3))) unsigned int*)lds, 16, 0, 0);
}

// ---------------- log_w precompute: logw = bf16(log(10*sigmoid(raw))) -------
__global__ __launch_bounds__(256) void k_logw(const float* __restrict__ raw,
                                              unsigned short* __restrict__ logw) {
  int i = blockIdx.x * 256 + threadIdx.x;
  float4 x = ((const float4*)raw)[i];
  ushort4 r;
  r.x = f2bf_rne(LN10 - log1pf(expf(-x.x)));
  r.y = f2bf_rne(LN10 - log1pf(expf(-x.y)));
  r.z = f2bf_rne(LN10 - log1pf(expf(-x.z)));
  r.w = f2bf_rne(LN10 - log1pf(expf(-x.w)));
  ((ushort4*)logw)[i] = r;
}

// ---------------- bit-pack: binary fp32 {0,1} -> 1 bit; popcount -> n_active
// 1 block per row; perfectly sequential coalesced float4 reads (the only
// pattern proven at ~6.3 TB/s). Word w bit j = binary[r][w*32+j].
__global__ __launch_bounds__(256) void k_pack(const float* __restrict__ binary,
                                              unsigned int* __restrict__ bits,
                                              float* __restrict__ nact) {
  const int r = blockIdx.x;
  const int t = threadIdx.x;
  const int lane = t & 63;
  const float4* src = (const float4*)(binary + (size_t)r * KDIM);
  unsigned int* wrow = bits + (size_t)r * WPR;
  float cnt = 0.f;
#pragma unroll
  for (int i = 0; i < 16; ++i) {
    float4 f = src[i * 256 + t];
    // values are exactly 0.0f or 1.0f; bit29 of 0x3F800000 is 1
    unsigned int nib = ((__float_as_uint(f.x) >> 29) & 1u) |
                       ((__float_as_uint(f.y) >> 28) & 2u) |
                       ((__float_as_uint(f.z) >> 27) & 4u) |
                       ((__float_as_uint(f.w) >> 26) & 8u);
    unsigned int v = nib, p;
    p = __shfl_xor(v, 1, 64); v = (lane & 1) ? (p | (v << 4)) : (v | (p << 4));
    p = __shfl_xor(v, 2, 64); v = (lane & 2) ? (p | (v << 8)) : (v | (p << 8));
    p = __shfl_xor(v, 4, 64); v = (lane & 4) ? (p | (v << 16)) : (v | (p << 16));
    if ((t & 7) == 0) wrow[i * 32 + (t >> 3)] = v;
    cnt += (float)__popc(v); // all 8 lanes of a group count the same word
  }
  cnt *= 0.125f;
  cnt += __shfl_xor(cnt, 1, 64);
  cnt += __shfl_xor(cnt, 2, 64);
  cnt += __shfl_xor(cnt, 4, 64);
  cnt += __shfl_xor(cnt, 8, 64);
  cnt += __shfl_xor(cnt, 16, 64);
  cnt += __shfl_xor(cnt, 32, 64);
  if (lane == 0) atomicAdd(&nact[r], cnt);
}

// ---------------- main MFMA GEMM: A from L2-resident bitmap -----------------
// grid (16 splits, 32 m-blocks) = 512 blocks = 2/CU; XCD = sx%8 -> per-XCD
// working set = B slice (1MB) + bit slice (0.5MB), L2-resident.
// Dyn LDS 78848: B dbuf 2x32KB | bit words [64][36] u32 | LUT [256] x 16B.
// A-frag: ds_read_b64 word pair -> byte (lhi) -> LUT -> short8 bf16 {0,1}.
// B: glds linear dest + pre-swizzled source (r5 pattern, 0 conflicts).
// Pipeline: dbuf + counted vmcnt(8) (hides L2 latency), 2 raw barriers/tile.
template <int PART>
__global__ __launch_bounds__(256) void k_gemm(
    const unsigned int* __restrict__ bits, const unsigned short* __restrict__ logw,
    float* __restrict__ outp) {
  extern __shared__ char smem[];
  char* const B0 = smem;
  char* const B1 = smem + 32768;
  unsigned int* const Wb = (unsigned int*)(smem + 65536); // [64][36]
  uint4* const LUT = (uint4*)(smem + 74752);              // [256]

  const int tid = threadIdx.x;
  const int wv = tid >> 6;
  const int lane = tid & 63;
  const int l15 = lane & 15;
  const int lhi = lane >> 4;
  const int sx = blockIdx.x;  // k-split
  const int m0 = blockIdx.y * BM;
  const int k0 = sx * KCHUNK;

  // --- init: LUT (byte -> 8 bf16) ---
  {
    unsigned int e0 = ((tid >> 0) & 1 ? 0x3F80u : 0u) | ((tid >> 1) & 1 ? 0x3F800000u : 0u);
    unsigned int e1 = ((tid >> 2) & 1 ? 0x3F80u : 0u) | ((tid >> 3) & 1 ? 0x3F800000u : 0u);
    unsigned int e2 = ((tid >> 4) & 1 ? 0x3F80u : 0u) | ((tid >> 5) & 1 ? 0x3F800000u : 0u);
    unsigned int e3 = ((tid >> 6) & 1 ? 0x3F80u : 0u) | ((tid >> 7) & 1 ? 0x3F800000u : 0u);
    LUT[tid] = (uint4){e0, e1, e2, e3};
  }
  // --- init: bit words for this block's [64 rows][32 words] slice ---
  {
    const unsigned int* gsrc =
        bits + (size_t)(m0 + (tid >> 2)) * WPR + sx * CW + (tid & 3) * 8;
    uint4 w0 = *(const uint4*)gsrc;
    uint4 w1 = *(const uint4*)(gsrc + 4);
    unsigned int* ld = Wb + (tid >> 2) * 36 + (tid & 3) * 8;
    *(uint4*)ld = w0;
    *(uint4*)(ld + 4) = w1;
  }
  __syncthreads();

  // B staging: instr i covers LDS rows wv*64+i*8..+8 (linear, lane*16);
  // source k-slot pre-swizzled: phys_slot = slot ^ (row&7)
  const unsigned short* bsrc =
      logw + (size_t)(wv * 64 + (lane >> 3)) * KDIM + k0 +
      (((lane & 7) ^ (lane >> 3)) << 3);
  const int rsw = (l15 & 7) << 4;

  f32x4 acc[4][4];
#pragma unroll
  for (int m = 0; m < 4; ++m)
#pragma unroll
    for (int n = 0; n < 4; ++n) acc[m][n] = f32x4{0.f, 0.f, 0.f, 0.f};

  auto BSTAGE = [&](int t, char* B) {
#pragma unroll
    for (int i = 0; i < 8; ++i)
      async16(B + (wv * 64 + i * 8) * 128, bsrc + (size_t)i * 8 * KDIM + t * BK);
  };
  auto COMPUTE = [&](const char* B, int t) {
    uint2 aw[4];
#pragma unroll
    for (int m = 0; m < 4; ++m)
      aw[m] = *(const uint2*)(Wb + (m * 16 + l15) * 36 + 2 * t);
#pragma unroll
    for (int ks = 0; ks < 2; ++ks) {
      const int koff = ((ks * 64) | (lhi * 16)) ^ rsw;
      short8 bf[4];
#pragma unroll
      for (int n = 0; n < 4; ++n)
        bf[n] = *(const short8*)(B + (wv * 64 + n * 16 + l15) * 128 + koff);
#pragma unroll
      for (int m = 0; m < 4; ++m) {
        unsigned int w = ks ? aw[m].y : aw[m].x;
        unsigned int byt = (w >> (lhi * 8)) & 0xffu;
        union { uint4 u; short8 s; } ex;
        ex.u = LUT[byt];
#pragma unroll
        for (int n = 0; n < 4; ++n)
          acc[m][n] = __builtin_amdgcn_mfma_f32_16x16x32_bf16(bf[n], ex.s,
                                                              acc[m][n], 0, 0, 0);
      }
    }
  };

  BSTAGE(0, B0);
  FENCE;
#pragma unroll 1
  for (int t = 0; t < NT; t += 2) {
    BSTAGE(t + 1, B1);
    FENCE; VMW8; BAR; FENCE;     // B(t) landed; B(t+1) in flight
    COMPUTE(B0, t);
    FENCE; BAR; FENCE;           // all waves done reading B0
    if (t + 2 < NT) {
      BSTAGE(t + 2, B0);
      FENCE; VMW8;
    } else {
      VMW0;
    }
    BAR; FENCE;                  // B(t+1) landed
    COMPUTE(B1, t + 1);
    FENCE; BAR; FENCE;           // all waves done reading B1
  }

  // D layout (swapped operands, verified r5): batch col = m*16+l15,
  // vocab row = wv*64 + n*16 + lhi*4 + i
  if (PART) {
#pragma unroll
    for (int m = 0; m < 4; ++m) {
      float* dst = outp + ((size_t)sx * BATCH + m0 + m * 16 + l15) * VOCAB +
                   wv * 64 + lhi * 4;
#pragma unroll
      for (int n = 0; n < 4; ++n)
        *(float4*)(dst + n * 16) =
            (float4){acc[m][n][0], acc[m][n][1], acc[m][n][2], acc[m][n][3]};
    }
  } else {
#pragma unroll
    for (int m = 0; m < 4; ++m)
#pragma unroll
      for (int n = 0; n < 4; ++n)
#pragma unroll
        for (int i = 0; i < 4; ++i)
          atomicAdd(&outp[(size_t)(m0 + m * 16 + l15) * VOCAB + wv * 64 +
                          n * 16 + lhi * 4 + i],
                    acc[m][n][i]);
  }
}

// ---------------- reduce: sum split partials, divide by n_active, exp -------
__global__ __launch_bounds__(256) void k_reduce(const float* __restrict__ part,
                                                const float* __restrict__ nact,
                                                float* __restrict__ out) {
  int b = blockIdx.x;
  int v = threadIdx.x;
  float sum = 0.f;
#pragma unroll
  for (int i = 0; i < S_SPLIT; ++i)
    sum += part[((size_t)i * BATCH + b) * VOCAB + v];
  out[(size_t)b * VOCAB + v] = expf(sum / fmaxf(nact[b], 1.f));
}

// ---------------- epilogue (atomic fallback path) ---------------------------
__global__ __launch_bounds__(256) void k_out(float* __restrict__ io,
                                             const float* __restrict__ nact) {
  int b = blockIdx.x;
  int v = threadIdx.x;
  float n = fmaxf(nact[b], 1.0f);
  size_t idx = (size_t)b * VOCAB + v;
  io[idx] = expf(io[idx] / n);
}

extern "C" void kernel_launch(void* const* d_in, const int* in_sizes, int n_in,
                              void* d_out, int out_size, void* d_ws, size_t ws_size,
                              hipStream_t stream) {
  const float* binary = (const float*)d_in[0];
  const float* raw = (const float*)d_in[1];
  float* out = (float*)d_out;
  char* ws = (char*)d_ws;

  const size_t LOGW_B = (size_t)VOCAB * KDIM * 2;            // 8 MB
  const size_t BITS_B = (size_t)BATCH * WPR * 4;             // 4 MB
  const size_t NACT_B = (size_t)BATCH * 4;                   // 8 KB
  const size_t PART_B = (size_t)S_SPLIT * BATCH * VOCAB * 4; // 32 MB
  unsigned short* logw = (unsigned short*)ws;
  unsigned int* bits = (unsigned int*)(ws + LOGW_B);
  float* nact = (float*)(ws + LOGW_B + BITS_B);
  float* part = (float*)(ws + LOGW_B + BITS_B + NACT_B);

  hipMemsetAsync(nact, 0, NACT_B, stream);
  k_logw<<<(VOCAB * KDIM / 4) / 256, 256, 0, stream>>>(raw, logw);
  k_pack<<<BATCH, 256, 0, stream>>>(binary, bits, nact);

  dim3 g(S_SPLIT, BATCH / BM);
  const size_t LDS_B = 78848;
  if (ws_size >= LOGW_B + BITS_B + NACT_B + PART_B) {
    k_gemm<1><<<g, 256, LDS_B, stream>>>(bits, logw, part);
    k_reduce<<<BATCH, VOCAB, 0, stream>>>(part, nact, out);
  } else {
    hipMemsetAsync(out, 0, (size_t)BATCH * VOCAB * sizeof(float), stream);
    k_gemm<0><<<g, 256, LDS_B, stream>>>(bits, logw, out);
    k_out<<<BATCH, VOCAB, 0, stream>>>(out, nact);
  }
}

// Round 7
// 241.916 us; speedup vs baseline: 1.0858x; 1.0067x over previous
//
#include <hip/hip_runtime.h>

#define BATCH 2048
#define VOCAB 256
#define KDIM 16384
#define WPR (KDIM / 32)          // 512 bit-words per row
#define BM 64
#define BK 64
#define S_SPLIT 16
#define KCHUNK (KDIM / S_SPLIT)  // 1024
#define NT (KCHUNK / BK)         // 16 K-tiles per block
#define CW (KCHUNK / 32)         // 32 words per row per chunk
#define WSTRIDE 34               // Wb row stride (u32) - even => 8B aligned b64
#define LN10 2.302585092994046f

typedef __attribute__((ext_vector_type(8))) short short8;
typedef __attribute__((ext_vector_type(4))) float f32x4;
typedef __attribute__((ext_vector_type(2))) unsigned short u16x2;

#define FENCE asm volatile("" ::: "memory")
#define BAR __builtin_amdgcn_s_barrier()
#define VMW8 asm volatile("s_waitcnt vmcnt(8)" ::: "memory")
#define VMW0 asm volatile("s_waitcnt vmcnt(0)" ::: "memory")

__device__ __forceinline__ unsigned short f2bf_rne(float f) {
  unsigned int u = __float_as_uint(f);
  u += 0x7fffu + ((u >> 16) & 1u);
  return (unsigned short)(u >> 16);
}

__device__ __forceinline__ void async16(void* lds, const void* g) {
  __builtin_amdgcn_global_load_lds(
      (const __attribute__((address_space(1))) unsigned int*)g,
      (__attribute__((address_space(3))) unsigned int*)lds, 16, 0, 0);
}

// packed u16 multiply (v_pk_mul_lo_u16); both products fit in 16 bits
__device__ __forceinline__ unsigned int pkmul(unsigned int a, unsigned int b) {
  union { unsigned int u; u16x2 h; } x, y, r;
  x.u = a; y.u = b;
  r.h = x.h * y.h;
  return r.u;
}

// ---------------- log_w precompute: logw = bf16(log(10*sigmoid(raw))) -------
__global__ __launch_bounds__(256) void k_logw(const float* __restrict__ raw,
                                              unsigned short* __restrict__ logw) {
  int i = blockIdx.x * 256 + threadIdx.x;
  float4 x = ((const float4*)raw)[i];
  ushort4 r;
  r.x = f2bf_rne(LN10 - log1pf(expf(-x.x)));
  r.y = f2bf_rne(LN10 - log1pf(expf(-x.y)));
  r.z = f2bf_rne(LN10 - log1pf(expf(-x.z)));
  r.w = f2bf_rne(LN10 - log1pf(expf(-x.w)));
  ((ushort4*)logw)[i] = r;
}

// ---------------- bit-pack: binary fp32 {0,1} -> 1 bit; per-wave popcounts --
// 1 block per row; perfectly sequential coalesced float4 reads.
// Word w bit j = binary[r][w*32+j]. Wave wv writes partial count nact4[r*4+wv].
__global__ __launch_bounds__(256) void k_pack(const float* __restrict__ binary,
                                              unsigned int* __restrict__ bits,
                                              float* __restrict__ nact4) {
  const int r = blockIdx.x;
  const int t = threadIdx.x;
  const int lane = t & 63;
  const float4* src = (const float4*)(binary + (size_t)r * KDIM);
  unsigned int* wrow = bits + (size_t)r * WPR;
  float cnt = 0.f;
#pragma unroll
  for (int i = 0; i < 16; ++i) {
    float4 f = src[i * 256 + t];
    // values are exactly 0.0f or 1.0f; bit 29 of 0x3F800000 is 1
    unsigned int nib = ((__float_as_uint(f.x) >> 29) & 1u) |
                       ((__float_as_uint(f.y) >> 28) & 2u) |
                       ((__float_as_uint(f.z) >> 27) & 4u) |
                       ((__float_as_uint(f.w) >> 26) & 8u);
    unsigned int v = nib, p;
    p = __shfl_xor(v, 1, 64); v = (lane & 1) ? (p | (v << 4)) : (v | (p << 4));
    p = __shfl_xor(v, 2, 64); v = (lane & 2) ? (p | (v << 8)) : (v | (p << 8));
    p = __shfl_xor(v, 4, 64); v = (lane & 4) ? (p | (v << 16)) : (v | (p << 16));
    if ((t & 7) == 0) wrow[i * 32 + (t >> 3)] = v;
    cnt += (float)__popc(v); // 8 lanes of a group count the same word
  }
  cnt *= 0.125f;
  cnt += __shfl_xor(cnt, 1, 64);
  cnt += __shfl_xor(cnt, 2, 64);
  cnt += __shfl_xor(cnt, 4, 64);
  cnt += __shfl_xor(cnt, 8, 64);
  cnt += __shfl_xor(cnt, 16, 64);
  cnt += __shfl_xor(cnt, 32, 64);
  if (lane == 0) nact4[r * 4 + (t >> 6)] = cnt; // unique writer, no memset
}

// ---------------- main MFMA GEMM: A expanded from L2-resident bitmap --------
// grid (16 splits, 32 m-blocks) = 512 blocks = 2/CU.
// Dyn LDS 74240: B dbuf 2x32KB | Wb bit-words [64][WSTRIDE] u32.
// A-frag expansion (no LDS, no LUT): rep = byte*0x01010101; per bf16-pair:
//   (rep & mask_j) -> halfwords {2^2j, 2^(2j+1)}; v_pk_mul_lo_u16 by
//   (0x3F80>>bit) -> exact bf16 1.0. 11 VALU per fragment.
// B: glds linear dest + pre-swizzled source (verified, 0 conflicts).
// Pipeline: dbuf + counted vmcnt(8), 2 raw barriers/tile.
template <int PART>
__global__ __launch_bounds__(256) void k_gemm(
    const unsigned int* __restrict__ bits, const unsigned short* __restrict__ logw,
    float* __restrict__ outp) {
  extern __shared__ char smem[];
  char* const B0 = smem;
  char* const B1 = smem + 32768;
  unsigned int* const Wb = (unsigned int*)(smem + 65536); // [64][WSTRIDE]

  const int tid = threadIdx.x;
  const int wv = tid >> 6;
  const int lane = tid & 63;
  const int l15 = lane & 15;
  const int lhi = lane >> 4;
  const int sh8 = lhi * 8;
  const int sx = blockIdx.x;  // k-split
  const int m0 = blockIdx.y * BM;
  const int k0 = sx * KCHUNK;

  // --- init: bit words for this block's [64 rows][32 words] slice ---
  {
    const unsigned int* gsrc =
        bits + (size_t)(m0 + (tid >> 2)) * WPR + sx * CW + (tid & 3) * 8;
    uint4 w0 = *(const uint4*)gsrc;
    uint4 w1 = *(const uint4*)(gsrc + 4);
    unsigned int* ld = Wb + (tid >> 2) * WSTRIDE + (tid & 3) * 8;
    ld[0] = w0.x; ld[1] = w0.y; ld[2] = w0.z; ld[3] = w0.w;
    ld[4] = w1.x; ld[5] = w1.y; ld[6] = w1.z; ld[7] = w1.w;
  }
  __syncthreads();

  // B staging: instr i covers LDS rows wv*64+i*8..+8 (linear, lane*16);
  // source k-slot pre-swizzled: phys_slot = slot ^ (row&7)
  const unsigned short* bsrc =
      logw + (size_t)(wv * 64 + (lane >> 3)) * KDIM + k0 +
      (((lane & 7) ^ (lane >> 3)) << 3);
  const int rsw = (l15 & 7) << 4;

  f32x4 acc[4][4];
#pragma unroll
  for (int m = 0; m < 4; ++m)
#pragma unroll
    for (int n = 0; n < 4; ++n) acc[m][n] = f32x4{0.f, 0.f, 0.f, 0.f};

  auto BSTAGE = [&](int t, char* B) {
#pragma unroll
    for (int i = 0; i < 8; ++i)
      async16(B + (wv * 64 + i * 8) * 128, bsrc + (size_t)i * 8 * KDIM + t * BK);
  };
  auto COMPUTE = [&](const char* B, int t) {
    uint2 aw[4];
#pragma unroll
    for (int m = 0; m < 4; ++m)
      aw[m] = *(const uint2*)(Wb + (m * 16 + l15) * WSTRIDE + 2 * t);
#pragma unroll
    for (int ks = 0; ks < 2; ++ks) {
      const int koff = ((ks * 64) | (lhi * 16)) ^ rsw;
      short8 bf[4];
#pragma unroll
      for (int n = 0; n < 4; ++n)
        bf[n] = *(const short8*)(B + (wv * 64 + n * 16 + l15) * 128 + koff);
#pragma unroll
      for (int m = 0; m < 4; ++m) {
        const unsigned int w = ks ? aw[m].y : aw[m].x;
        const unsigned int rep = ((w >> sh8) & 0xffu) * 0x01010101u;
        union { unsigned int u[4]; short8 s; } ex;
        ex.u[0] = pkmul(rep & 0x00020001u, 0x1FC03F80u);
        ex.u[1] = pkmul(rep & 0x00080004u, 0x07F00FE0u);
        ex.u[2] = pkmul(rep & 0x00200010u, 0x01FC03F8u);
        ex.u[3] = pkmul(rep & 0x00800040u, 0x007F00FEu);
#pragma unroll
        for (int n = 0; n < 4; ++n)
          acc[m][n] = __builtin_amdgcn_mfma_f32_16x16x32_bf16(bf[n], ex.s,
                                                              acc[m][n], 0, 0, 0);
      }
    }
  };

  BSTAGE(0, B0);
  FENCE;
#pragma unroll 1
  for (int t = 0; t < NT; t += 2) {
    BSTAGE(t + 1, B1);
    FENCE; VMW8; BAR; FENCE;     // B(t) landed; B(t+1) in flight
    COMPUTE(B0, t);
    FENCE; BAR; FENCE;           // all waves done reading B0
    if (t + 2 < NT) {
      BSTAGE(t + 2, B0);
      FENCE; VMW8;
    } else {
      VMW0;
    }
    BAR; FENCE;                  // B(t+1) landed
    COMPUTE(B1, t + 1);
    FENCE; BAR; FENCE;           // all waves done reading B1
  }

  // D layout (swapped operands): batch col = m*16+l15,
  // vocab row = wv*64 + n*16 + lhi*4 + i
  if (PART) {
#pragma unroll
    for (int m = 0; m < 4; ++m) {
      float* dst = outp + ((size_t)sx * BATCH + m0 + m * 16 + l15) * VOCAB +
                   wv * 64 + lhi * 4;
#pragma unroll
      for (int n = 0; n < 4; ++n)
        *(float4*)(dst + n * 16) =
            (float4){acc[m][n][0], acc[m][n][1], acc[m][n][2], acc[m][n][3]};
    }
  } else {
#pragma unroll
    for (int m = 0; m < 4; ++m)
#pragma unroll
      for (int n = 0; n < 4; ++n)
#pragma unroll
        for (int i = 0; i < 4; ++i)
          atomicAdd(&outp[(size_t)(m0 + m * 16 + l15) * VOCAB + wv * 64 +
                          n * 16 + lhi * 4 + i],
                    acc[m][n][i]);
  }
}

// ---------------- reduce: sum split partials, divide by n_active, exp -------
__global__ __launch_bounds__(256) void k_reduce(const float* __restrict__ part,
                                                const float* __restrict__ nact4,
                                                float* __restrict__ out) {
  int b = blockIdx.x;
  int v = threadIdx.x;
  float sum = 0.f;
#pragma unroll
  for (int i = 0; i < S_SPLIT; ++i)
    sum += part[((size_t)i * BATCH + b) * VOCAB + v];
  float n = nact4[b * 4] + nact4[b * 4 + 1] + nact4[b * 4 + 2] + nact4[b * 4 + 3];
  out[(size_t)b * VOCAB + v] = expf(sum / fmaxf(n, 1.f));
}

// ---------------- epilogue (atomic fallback path) ---------------------------
__global__ __launch_bounds__(256) void k_out(float* __restrict__ io,
                                             const float* __restrict__ nact4) {
  int b = blockIdx.x;
  int v = threadIdx.x;
  float n = nact4[b * 4] + nact4[b * 4 + 1] + nact4[b * 4 + 2] + nact4[b * 4 + 3];
  n = fmaxf(n, 1.0f);
  size_t idx = (size_t)b * VOCAB + v;
  io[idx] = expf(io[idx] / n);
}

extern "C" void kernel_launch(void* const* d_in, const int* in_sizes, int n_in,
                              void* d_out, int out_size, void* d_ws, size_t ws_size,
                              hipStream_t stream) {
  const float* binary = (const float*)d_in[0];
  const float* raw = (const float*)d_in[1];
  float* out = (float*)d_out;
  char* ws = (char*)d_ws;

  const size_t LOGW_B = (size_t)VOCAB * KDIM * 2;            // 8 MB
  const size_t BITS_B = (size_t)BATCH * WPR * 4;             // 4 MB
  const size_t NACT_B = (size_t)BATCH * 4 * 4;               // 32 KB
  const size_t PART_B = (size_t)S_SPLIT * BATCH * VOCAB * 4; // 32 MB
  unsigned short* logw = (unsigned short*)ws;
  unsigned int* bits = (unsigned int*)(ws + LOGW_B);
  float* nact4 = (float*)(ws + LOGW_B + BITS_B);
  float* part = (float*)(ws + LOGW_B + BITS_B + NACT_B);

  k_logw<<<(VOCAB * KDIM / 4) / 256, 256, 0, stream>>>(raw, logw);
  k_pack<<<BATCH, 256, 0, stream>>>(binary, bits, nact4);

  dim3 g(S_SPLIT, BATCH / BM);
  const size_t LDS_B = 65536 + 64 * WSTRIDE * 4; // 74240
  if (ws_size >= LOGW_B + BITS_B + NACT_B + PART_B) {
    k_gemm<1><<<g, 256, LDS_B, stream>>>(bits, logw, part);
    k_reduce<<<BATCH, VOCAB, 0, stream>>>(part, nact4, out);
  } else {
    hipMemsetAsync(out, 0, (size_t)BATCH * VOCAB * sizeof(float), stream);
    k_gemm<0><<<g, 256, LDS_B, stream>>>(bits, logw, out);
    k_out<<<BATCH, VOCAB, 0, stream>>>(out, nact4);
  }
}